// Round 16
// baseline (77.380 us; speedup 1.0000x reference)
//
#include <hip/hip_runtime.h>

#define NN 50000
#define NE 1600000
#define DD 64
#define RB 32                            // rows per bucket
#define NBK 1563                         // ceil(NN/RB)
#define BINS 2048                        // padded bin count (>= NBK)
#define EPB 4096                         // edges per scatter block
#define NBLKA 391                        // ceil(NE/EPB)
#define CAP 1536                         // max padded edges per bucket (mean 1024)
#define G4 800000                        // float4 groups in x
#define CONVB 196                        // convert blocks (196*1024*4 >= G4)

__device__ __forceinline__ unsigned f2bf(float f) {   // RNE
    unsigned u = __float_as_uint(f);
    u += 0x7FFFu + ((u >> 16) & 1u);
    return (u >> 16) & 0xFFFFu;
}

// ---------- K1: bucket scatter into CAP-strided private regions + x->bf16 ----
// gcur (zeroed) gives each block a run offset via atomicAdd; after the kernel
// gcur[b] == edge count of bucket b. pkv[b*CAP + i] = (val_bf16<<16)|col.
__global__ __launch_bounds__(1024) void scatter_conv(
    const int* __restrict__ erow, const int* __restrict__ ecol,
    const float* __restrict__ evals, const float* __restrict__ x,
    uint2* __restrict__ xb, int* __restrict__ gcur,
    unsigned* __restrict__ pkv, unsigned char* __restrict__ rlb)
{
    int tid = threadIdx.x;
    if (blockIdx.x >= NBLKA) {               // convert blocks: x -> bf16x4
        int t = (blockIdx.x - NBLKA) * 1024 + tid;
        const float4* x4 = reinterpret_cast<const float4*>(x);
        #pragma unroll
        for (int i = 0; i < 4; ++i) {
            int g = i * (CONVB * 1024) + t;
            if (g < G4) {
                float4 v = x4[g];
                uint2 o;
                o.x = f2bf(v.x) | (f2bf(v.y) << 16);
                o.y = f2bf(v.z) | (f2bf(v.w) << 16);
                xb[g] = o;
            }
        }
        return;
    }

    __shared__ int hist[BINS];              // 8 KB
    __shared__ int lstart[BINS];            // 8 KB
    __shared__ int gbase[BINS];             // 8 KB
    __shared__ unsigned datap[EPB];         // 16 KB packed (val_bf16<<16|col)
    __shared__ unsigned char datarl[EPB];   // 4 KB row_local
    __shared__ unsigned short sbkt[EPB];    // 8 KB bucket id

    for (int i = tid; i < BINS; i += 1024) hist[i] = 0;
    __syncthreads();

    int base = blockIdx.x * EPB;
    int r[4], c[4], bk[4]; float v[4];
    #pragma unroll
    for (int i = 0; i < 4; ++i) {
        int e = base + i * 1024 + tid;
        if (e < NE) {
            r[i] = erow[e]; c[i] = ecol[e]; v[i] = evals[e];
            bk[i] = r[i] >> 5;              // 32-row buckets
            atomicAdd(&hist[bk[i]], 1);
        } else bk[i] = -1;
    }
    __syncthreads();

    if (tid < 64) {                         // wave 0: scan 2048 bins, 32/lane
        int s = 0;                          // (LDS-resident, no big reg array)
        for (int i = 0; i < 32; ++i) s += hist[tid * 32 + i];
        int vv = s;
        #pragma unroll
        for (int off = 1; off < 64; off <<= 1) {
            int u = __shfl_up(vv, off, 64);
            if (tid >= off) vv += u;
        }
        int run = vv - s;
        for (int i = 0; i < 32; ++i) {
            int cbin = hist[tid * 32 + i];
            lstart[tid * 32 + i] = run;
            run += cbin;
        }
    }
    __syncthreads();

    for (int i = tid; i < BINS; i += 1024) {   // reserve run in bucket region
        int cnt = hist[i];
        gbase[i] = cnt ? atomicAdd(&gcur[i], cnt) : 0;
        hist[i] = lstart[i];
    }
    __syncthreads();

    #pragma unroll
    for (int i = 0; i < 4; ++i) {           // scatter into LDS, bucket-grouped
        if (bk[i] >= 0) {
            int p = atomicAdd(&hist[bk[i]], 1);
            datap[p]  = (f2bf(v[i]) << 16) | (unsigned)c[i];
            datarl[p] = (unsigned char)(r[i] & (RB - 1));
            sbkt[p]   = (unsigned short)bk[i];
        }
    }
    __syncthreads();

    int total = NE - base; if (total > EPB) total = EPB;
    #pragma unroll
    for (int i = 0; i < 4; ++i) {           // coalesced copy-out of runs
        int slot = i * 1024 + tid;
        if (slot < total) {
            int bb = sbkt[slot];
            int dst = bb * CAP + gbase[bb] + slot - lstart[bb];
            pkv[dst] = datap[slot];
            rlb[dst] = datarl[slot];
        }
    }
}

// ---------- K2: fused LDS row-sort + gather SpMM + h0 mix + GEMM -------------
// One block per 32-row bucket, 256 threads, 1563 blocks (~6/CU, ~7 fit).
// Sort: LDS counting sort by row_local, rows padded to x8 (zero dummies).
// Gather: 8 row-slots x 4 passes; 2x16-lane groups/row; desc from LDS pkbuf.
// out = ((1-s)*A@x + s*h0) @ (theta*W + (1-theta)*I)
__global__ __launch_bounds__(256) void sort_spmm_gemm(
    const int* __restrict__ gcur, const unsigned* __restrict__ pkv,
    const unsigned char* __restrict__ rlb,
    const uint2* __restrict__ xb, const float* __restrict__ h0,
    const float* __restrict__ W,  const float* __restrict__ lamda,
    const float* __restrict__ s_ptr, const int* __restrict__ l_ptr,
    float* __restrict__ out)
{
    __shared__ unsigned pkbuf[CAP];         // 6 KB row-sorted packed edges
    __shared__ float Wp[DD * DD];           // 16 KB
    __shared__ int rhist[RB];
    __shared__ int rstart[RB + 1];

    int tid = threadIdx.x;
    int b = blockIdx.x;
    int base = b * CAP;
    int count = gcur[b];

    float theta = lamda[0] / (float)l_ptr[0];
    float s     = s_ptr[0];
    float oms   = 1.0f - s;

    for (int i = tid; i < DD * DD; i += 256) {
        int k = i >> 6, j = i & 63;
        float wv = theta * W[i];
        if (k == j) wv += (1.0f - theta);
        Wp[i] = wv;
    }
    if (tid < RB) rhist[tid] = 0;
    __syncthreads();

    // --- sort phase A: load edges to regs + row histogram
    unsigned av[CAP / 256];                 // 6 edges max per thread
    int rl[CAP / 256];
    #pragma unroll
    for (int i = 0; i < CAP / 256; ++i) {
        int idx = i * 256 + tid;
        if (idx < count) {
            av[i] = pkv[base + idx];
            rl[i] = rlb[base + idx];
            atomicAdd(&rhist[rl[i]], 1);
        } else rl[i] = -1;
    }
    __syncthreads();

    if (tid < 64) {                         // exclusive scan of PADDED counts
        int pc = (tid < RB) ? ((rhist[tid] + 7) & ~7) : 0;
        int vv = pc;
        #pragma unroll
        for (int off = 1; off < 64; off <<= 1) {
            int u = __shfl_up(vv, off, 64);
            if (tid >= off) vv += u;
        }
        if (tid < RB) rstart[tid] = vv - pc;
        if (tid == RB - 1) rstart[RB] = vv;
    }
    __syncthreads();
    if (tid < RB) rhist[tid] = rstart[tid]; // cursors
    __syncthreads();

    // --- sort phase B: scatter into LDS at row-sorted positions
    #pragma unroll
    for (int i = 0; i < CAP / 256; ++i)
        if (rl[i] >= 0) {
            int p = atomicAdd(&rhist[rl[i]], 1);
            pkbuf[p] = av[i];
        }
    __syncthreads();
    if (tid < RB)                           // zero-fill pad gaps (<=7 per row)
        for (int idx = rhist[tid]; idx < rstart[tid + 1]; ++idx)
            pkbuf[idx] = 0;                 // val_bf16=0 -> fmaf adds 0
    __syncthreads();

    // --- gather phase: 8 row-slots, 4 passes; proven round-13/15 body
    int f4     = tid & 15;
    int parity = (tid >> 4) & 1;
    int gb     = tid & 48;
    int slot   = tid >> 5;                  // 0..7

    #define FMA1(U, Q)                                                      \
        {                                                                   \
            float vv = __uint_as_float((U) & 0xFFFF0000u);                  \
            acc.x = fmaf(vv, __uint_as_float((Q).x << 16), acc.x);          \
            acc.y = fmaf(vv, __uint_as_float((Q).x & 0xFFFF0000u), acc.y);  \
            acc.z = fmaf(vv, __uint_as_float((Q).y << 16), acc.z);          \
            acc.w = fmaf(vv, __uint_as_float((Q).y & 0xFFFF0000u), acc.w);  \
        }

    #pragma unroll
    for (int pass = 0; pass < 4; ++pass) {
        int rr = pass * 8 + slot;           // row_local 0..31
        int r  = b * RB + rr;
        if (r < NN) {
            int e0  = rstart[rr];
            int end = rstart[rr + 1];

            float4 acc = make_float4(0.f, 0.f, 0.f, 0.f);
            for (int e = e0 + parity * 8; e < end; e += 16) {
                uint4 ua = *reinterpret_cast<const uint4*>(&pkbuf[e]);     // broadcast
                uint4 ub = *reinterpret_cast<const uint4*>(&pkbuf[e + 4]);
                uint2 q0 = xb[(size_t)(ua.x & 0xFFFFu) * 16 + f4];
                uint2 q1 = xb[(size_t)(ua.y & 0xFFFFu) * 16 + f4];
                uint2 q2 = xb[(size_t)(ua.z & 0xFFFFu) * 16 + f4];
                uint2 q3 = xb[(size_t)(ua.w & 0xFFFFu) * 16 + f4];
                uint2 q4 = xb[(size_t)(ub.x & 0xFFFFu) * 16 + f4];
                uint2 q5 = xb[(size_t)(ub.y & 0xFFFFu) * 16 + f4];
                uint2 q6 = xb[(size_t)(ub.z & 0xFFFFu) * 16 + f4];
                uint2 q7 = xb[(size_t)(ub.w & 0xFFFFu) * 16 + f4];
                FMA1(ua.x, q0); FMA1(ua.y, q1); FMA1(ua.z, q2); FMA1(ua.w, q3);
                FMA1(ub.x, q4); FMA1(ub.y, q5); FMA1(ub.z, q6); FMA1(ub.w, q7);
            }

            // combine the two half-row partials
            acc.x += __shfl_xor(acc.x, 16, 64);
            acc.y += __shfl_xor(acc.y, 16, 64);
            acc.z += __shfl_xor(acc.z, 16, 64);
            acc.w += __shfl_xor(acc.w, 16, 64);

            float4 hb = *reinterpret_cast<const float4*>(h0 + (size_t)r * DD + f4 * 4);
            float4 sup;
            sup.x = oms * acc.x + s * hb.x;
            sup.y = oms * acc.y + s * hb.y;
            sup.z = oms * acc.z + s * hb.z;
            sup.w = oms * acc.w + s * hb.w;

            // k-split GEMM: parity group does k in [parity*32, parity*32+32)
            float4 o = make_float4(0.f, 0.f, 0.f, 0.f);
            #pragma unroll
            for (int kk = 0; kk < 32; ++kk) {
                int k = parity * 32 + kk;
                float comp = ((kk & 3) == 0) ? sup.x :
                             ((kk & 3) == 1) ? sup.y :
                             ((kk & 3) == 2) ? sup.z : sup.w;
                float sk = __shfl(comp, gb + parity * 8 + (kk >> 2), 64);
                float4 w = *reinterpret_cast<const float4*>(&Wp[k * DD + f4 * 4]);
                o.x = fmaf(sk, w.x, o.x);
                o.y = fmaf(sk, w.y, o.y);
                o.z = fmaf(sk, w.z, o.z);
                o.w = fmaf(sk, w.w, o.w);
            }
            o.x += __shfl_xor(o.x, 16, 64);
            o.y += __shfl_xor(o.y, 16, 64);
            o.z += __shfl_xor(o.z, 16, 64);
            o.w += __shfl_xor(o.w, 16, 64);

            if (parity == 0)
                *reinterpret_cast<float4*>(out + (size_t)r * DD + f4 * 4) = o;
        }
    }
    #undef FMA1
}

extern "C" void kernel_launch(void* const* d_in, const int* in_sizes, int n_in,
                              void* d_out, int out_size, void* d_ws, size_t ws_size,
                              hipStream_t stream) {
    const float* x     = (const float*)d_in[0];
    const float* h0    = (const float*)d_in[1];
    const float* evals = (const float*)d_in[2];
    const float* W     = (const float*)d_in[3];
    const int*   erow  = (const int*)d_in[4];
    const int*   ecol  = (const int*)d_in[5];
    const float* lamda = (const float*)d_in[6];
    const float* s_ptr = (const float*)d_in[7];
    const int*   l_ptr = (const int*)d_in[8];
    float* out = (float*)d_out;

    // ws: gcur[2048] | pkv[NBK*CAP] u32 | rlb[NBK*CAP] u8 | xb bf16 (~18.4 MB)
    char* ws = (char*)d_ws;
    int*           gcur = (int*)ws;                              // 8192 B
    unsigned*      pkv  = (unsigned*)(ws + 8192);                // 9.6 MB
    unsigned char* rlb  = (unsigned char*)(ws + 8192 + (size_t)NBK * CAP * 4);
    uint2*         xb   = (uint2*)(ws + 8192 + (size_t)NBK * CAP * 5 + 4);  // 8B-aligned (NBK*CAP*5 = 12004, +4 pads)

    hipMemsetAsync(gcur, 0, 8192, stream);

    scatter_conv  <<<NBLKA + CONVB, 1024, 0, stream>>>(erow, ecol, evals, x, xb,
                                                       gcur, pkv, rlb);
    sort_spmm_gemm<<<NBK, 256, 0, stream>>>(gcur, pkv, rlb, xb, h0, W,
                                            lamda, s_ptr, l_ptr, out);
}

// Round 17
// 67.978 us; speedup vs baseline: 1.1383x; 1.1383x over previous
//
#include <hip/hip_runtime.h>

#define NN 50000
#define NE 1600000
#define DD 64
#define RB 64                            // rows per bucket
#define NBK 782                          // ceil(NN/RB)
#define BINS 1024                        // padded bin count (>= NBK)
#define EPB 4096                         // edges per scatter block
#define NBLKA 391                        // ceil(NE/EPB)
#define CAP 3072                         // max padded edges per bucket (mean 2048, +22 sigma)
#define G4 800000                        // float4 groups in x
#define CONVB 196                        // convert blocks (196*1024*4 >= G4)

__device__ __forceinline__ unsigned f2bf(float f) {   // RNE
    unsigned u = __float_as_uint(f);
    u += 0x7FFFu + ((u >> 16) & 1u);
    return (u >> 16) & 0xFFFFu;
}

// ---------- K1: bucket scatter into CAP-strided private regions + x->bf16 ----
// gcur (zeroed) gives each block a run offset via atomicAdd; after the kernel
// gcur[b] == edge count of bucket b. pkv[b*CAP + i] = (val_bf16<<16)|col.
__global__ __launch_bounds__(1024) void scatter_conv(
    const int* __restrict__ erow, const int* __restrict__ ecol,
    const float* __restrict__ evals, const float* __restrict__ x,
    uint2* __restrict__ xb, int* __restrict__ gcur,
    unsigned* __restrict__ pkv, unsigned char* __restrict__ rlb)
{
    int tid = threadIdx.x;
    if (blockIdx.x >= NBLKA) {               // convert blocks: x -> bf16x4
        int t = (blockIdx.x - NBLKA) * 1024 + tid;
        const float4* x4 = reinterpret_cast<const float4*>(x);
        #pragma unroll
        for (int i = 0; i < 4; ++i) {
            int g = i * (CONVB * 1024) + t;
            if (g < G4) {
                float4 v = x4[g];
                uint2 o;
                o.x = f2bf(v.x) | (f2bf(v.y) << 16);
                o.y = f2bf(v.z) | (f2bf(v.w) << 16);
                xb[g] = o;
            }
        }
        return;
    }

    __shared__ int hist[BINS];              // 4 KB
    __shared__ int lstart[BINS];            // 4 KB
    __shared__ int gbase[BINS];             // 4 KB
    __shared__ unsigned datap[EPB];         // 16 KB packed (val_bf16<<16|col)
    __shared__ unsigned char datarl[EPB];   // 4 KB row_local
    __shared__ unsigned short sbkt[EPB];    // 8 KB bucket id

    if (tid < BINS) hist[tid] = 0;
    __syncthreads();

    int base = blockIdx.x * EPB;
    int r[4], c[4], bk[4]; float v[4];
    #pragma unroll
    for (int i = 0; i < 4; ++i) {
        int e = base + i * 1024 + tid;
        if (e < NE) {
            r[i] = erow[e]; c[i] = ecol[e]; v[i] = evals[e];
            bk[i] = r[i] >> 6;              // 64-row buckets
            atomicAdd(&hist[bk[i]], 1);
        } else bk[i] = -1;
    }
    __syncthreads();

    if (tid < 64) {                         // wave 0: scan 1024 bins, 16/lane
        int cc[16], s = 0;
        #pragma unroll
        for (int i = 0; i < 16; ++i) { cc[i] = hist[tid * 16 + i]; s += cc[i]; }
        int vv = s;
        #pragma unroll
        for (int off = 1; off < 64; off <<= 1) {
            int u = __shfl_up(vv, off, 64);
            if (tid >= off) vv += u;
        }
        int run = vv - s;
        #pragma unroll
        for (int i = 0; i < 16; ++i) { lstart[tid * 16 + i] = run; run += cc[i]; }
    }
    __syncthreads();

    if (tid < BINS) {                       // reserve run in bucket's region
        int cnt = hist[tid];
        gbase[tid] = cnt ? atomicAdd(&gcur[tid], cnt) : 0;
        hist[tid] = lstart[tid];
    }
    __syncthreads();

    #pragma unroll
    for (int i = 0; i < 4; ++i) {           // scatter into LDS, bucket-grouped
        if (bk[i] >= 0) {
            int p = atomicAdd(&hist[bk[i]], 1);
            datap[p]  = (f2bf(v[i]) << 16) | (unsigned)c[i];
            datarl[p] = (unsigned char)(r[i] & (RB - 1));
            sbkt[p]   = (unsigned short)bk[i];
        }
    }
    __syncthreads();

    int total = NE - base; if (total > EPB) total = EPB;
    #pragma unroll
    for (int i = 0; i < 4; ++i) {           // coalesced copy-out of runs
        int slot = i * 1024 + tid;
        if (slot < total) {
            int bb = sbkt[slot];
            int dst = bb * CAP + gbase[bb] + slot - lstart[bb];
            pkv[dst] = datap[slot];
            rlb[dst] = datarl[slot];
        }
    }
}

// ---------- K2: fused LDS row-sort + gather SpMM + h0 mix + GEMM -------------
// One block per 64-row bucket, 512 threads, 782 blocks (all co-resident).
// Sort: LDS counting sort by row_local, rows padded to x8 (zero dummies).
// Gather: 16 row-slots x 4 passes; 2x16-lane groups/row; desc from LDS pkbuf.
// out = ((1-s)*A@x + s*h0) @ (theta*W + (1-theta)*I)
__global__ __launch_bounds__(512) void sort_spmm_gemm(
    const int* __restrict__ gcur, const unsigned* __restrict__ pkv,
    const unsigned char* __restrict__ rlb,
    const uint2* __restrict__ xb, const float* __restrict__ h0,
    const float* __restrict__ W,  const float* __restrict__ lamda,
    const float* __restrict__ s_ptr, const int* __restrict__ l_ptr,
    float* __restrict__ out)
{
    __shared__ unsigned pkbuf[CAP];         // 12 KB row-sorted packed edges
    __shared__ float Wp[DD * DD];           // 16 KB
    __shared__ int rhist[RB];
    __shared__ int rstart[RB + 1];

    int tid = threadIdx.x;
    int b = blockIdx.x;
    int base = b * CAP;
    int count = gcur[b];

    float theta = lamda[0] / (float)l_ptr[0];
    float s     = s_ptr[0];
    float oms   = 1.0f - s;

    for (int i = tid; i < DD * DD; i += 512) {
        int k = i >> 6, j = i & 63;
        float wv = theta * W[i];
        if (k == j) wv += (1.0f - theta);
        Wp[i] = wv;
    }
    if (tid < RB) rhist[tid] = 0;
    __syncthreads();

    // --- sort phase A: load edges to regs + row histogram
    unsigned av[CAP / 512];                 // 6 edges max per thread
    int rl[CAP / 512];
    #pragma unroll
    for (int i = 0; i < CAP / 512; ++i) {
        int idx = i * 512 + tid;
        if (idx < count) {
            av[i] = pkv[base + idx];
            rl[i] = rlb[base + idx];
            atomicAdd(&rhist[rl[i]], 1);
        } else rl[i] = -1;
    }
    __syncthreads();

    if (tid < 64) {                         // exclusive scan of PADDED counts
        int pc = (rhist[tid] + 7) & ~7;     // 64 bins, 1 per lane
        int vv = pc;
        #pragma unroll
        for (int off = 1; off < 64; off <<= 1) {
            int u = __shfl_up(vv, off, 64);
            if (tid >= off) vv += u;
        }
        rstart[tid] = vv - pc;
        if (tid == 63) rstart[RB] = vv;
    }
    __syncthreads();
    if (tid < RB) rhist[tid] = rstart[tid]; // cursors
    __syncthreads();

    // --- sort phase B: scatter into LDS at row-sorted positions
    #pragma unroll
    for (int i = 0; i < CAP / 512; ++i)
        if (rl[i] >= 0) {
            int p = atomicAdd(&rhist[rl[i]], 1);
            pkbuf[p] = av[i];
        }
    __syncthreads();
    if (tid < RB)                           // zero-fill pad gaps (<=7 per row)
        for (int idx = rhist[tid]; idx < rstart[tid + 1]; ++idx)
            pkbuf[idx] = 0;                 // val_bf16=0 -> fmaf adds 0
    __syncthreads();

    // --- gather phase: 16 row-slots, 4 passes; round-13 proven body
    int f4     = tid & 15;
    int parity = (tid >> 4) & 1;
    int gb     = tid & 48;
    int slot   = tid >> 5;                  // 0..15

    #define FMA1(U, Q)                                                      \
        {                                                                   \
            float vv = __uint_as_float((U) & 0xFFFF0000u);                  \
            acc.x = fmaf(vv, __uint_as_float((Q).x << 16), acc.x);          \
            acc.y = fmaf(vv, __uint_as_float((Q).x & 0xFFFF0000u), acc.y);  \
            acc.z = fmaf(vv, __uint_as_float((Q).y << 16), acc.z);          \
            acc.w = fmaf(vv, __uint_as_float((Q).y & 0xFFFF0000u), acc.w);  \
        }

    #pragma unroll
    for (int pass = 0; pass < 4; ++pass) {
        int rr = pass * 16 + slot;          // row_local 0..63
        int r  = b * RB + rr;
        if (r < NN) {
            int e0  = rstart[rr];
            int end = rstart[rr + 1];

            float4 acc = make_float4(0.f, 0.f, 0.f, 0.f);
            for (int e = e0 + parity * 8; e < end; e += 16) {
                uint4 ua = *reinterpret_cast<const uint4*>(&pkbuf[e]);     // broadcast
                uint4 ub = *reinterpret_cast<const uint4*>(&pkbuf[e + 4]);
                uint2 q0 = xb[(size_t)(ua.x & 0xFFFFu) * 16 + f4];
                uint2 q1 = xb[(size_t)(ua.y & 0xFFFFu) * 16 + f4];
                uint2 q2 = xb[(size_t)(ua.z & 0xFFFFu) * 16 + f4];
                uint2 q3 = xb[(size_t)(ua.w & 0xFFFFu) * 16 + f4];
                uint2 q4 = xb[(size_t)(ub.x & 0xFFFFu) * 16 + f4];
                uint2 q5 = xb[(size_t)(ub.y & 0xFFFFu) * 16 + f4];
                uint2 q6 = xb[(size_t)(ub.z & 0xFFFFu) * 16 + f4];
                uint2 q7 = xb[(size_t)(ub.w & 0xFFFFu) * 16 + f4];
                FMA1(ua.x, q0); FMA1(ua.y, q1); FMA1(ua.z, q2); FMA1(ua.w, q3);
                FMA1(ub.x, q4); FMA1(ub.y, q5); FMA1(ub.z, q6); FMA1(ub.w, q7);
            }

            // combine the two half-row partials
            acc.x += __shfl_xor(acc.x, 16, 64);
            acc.y += __shfl_xor(acc.y, 16, 64);
            acc.z += __shfl_xor(acc.z, 16, 64);
            acc.w += __shfl_xor(acc.w, 16, 64);

            float4 hb = *reinterpret_cast<const float4*>(h0 + (size_t)r * DD + f4 * 4);
            float4 sup;
            sup.x = oms * acc.x + s * hb.x;
            sup.y = oms * acc.y + s * hb.y;
            sup.z = oms * acc.z + s * hb.z;
            sup.w = oms * acc.w + s * hb.w;

            // k-split GEMM: parity group does k in [parity*32, parity*32+32)
            float4 o = make_float4(0.f, 0.f, 0.f, 0.f);
            #pragma unroll
            for (int kk = 0; kk < 32; ++kk) {
                int k = parity * 32 + kk;
                float comp = ((kk & 3) == 0) ? sup.x :
                             ((kk & 3) == 1) ? sup.y :
                             ((kk & 3) == 2) ? sup.z : sup.w;
                float sk = __shfl(comp, gb + parity * 8 + (kk >> 2), 64);
                float4 w = *reinterpret_cast<const float4*>(&Wp[k * DD + f4 * 4]);
                o.x = fmaf(sk, w.x, o.x);
                o.y = fmaf(sk, w.y, o.y);
                o.z = fmaf(sk, w.z, o.z);
                o.w = fmaf(sk, w.w, o.w);
            }
            o.x += __shfl_xor(o.x, 16, 64);
            o.y += __shfl_xor(o.y, 16, 64);
            o.z += __shfl_xor(o.z, 16, 64);
            o.w += __shfl_xor(o.w, 16, 64);

            if (parity == 0)
                *reinterpret_cast<float4*>(out + (size_t)r * DD + f4 * 4) = o;
        }
    }
    #undef FMA1
}

extern "C" void kernel_launch(void* const* d_in, const int* in_sizes, int n_in,
                              void* d_out, int out_size, void* d_ws, size_t ws_size,
                              hipStream_t stream) {
    const float* x     = (const float*)d_in[0];
    const float* h0    = (const float*)d_in[1];
    const float* evals = (const float*)d_in[2];
    const float* W     = (const float*)d_in[3];
    const int*   erow  = (const int*)d_in[4];
    const int*   ecol  = (const int*)d_in[5];
    const float* lamda = (const float*)d_in[6];
    const float* s_ptr = (const float*)d_in[7];
    const int*   l_ptr = (const int*)d_in[8];
    float* out = (float*)d_out;

    // ws: gcur[1024] | pkv[NBK*CAP] u32 | rlb[NBK*CAP] u8 | xb bf16 (~18.4 MB)
    char* ws = (char*)d_ws;
    int*           gcur = (int*)ws;                              // 4096 B
    unsigned*      pkv  = (unsigned*)(ws + 4096);                // 9.61 MB
    unsigned char* rlb  = (unsigned char*)(ws + 4096 + (size_t)NBK * CAP * 4);
    uint2*         xb   = (uint2*)(ws + 4096 + (size_t)NBK * CAP * 5);  // 8B-aligned

    hipMemsetAsync(gcur, 0, 4096, stream);

    scatter_conv  <<<NBLKA + CONVB, 1024, 0, stream>>>(erow, ecol, evals, x, xb,
                                                       gcur, pkv, rlb);
    sort_spmm_gemm<<<NBK, 512, 0, stream>>>(gcur, pkv, rlb, xb, h0, W,
                                            lamda, s_ptr, l_ptr, out);
}